// Round 3
// baseline (500.594 us; speedup 1.0000x reference)
//
#include <hip/hip_runtime.h>
#include <hip/hip_bf16.h>

#define NEG_SLOPE 0.2f
#define IN_DIM 512
#define HID 128
#define HEADS 4
#define D1 (HEADS * HID)   // 512
#define OUT_DIM 64

// ---------------------------------------------------------------------------
// Zero an int buffer
// ---------------------------------------------------------------------------
__global__ void zero_int_kernel(int* __restrict__ p, int n) {
    int i = blockIdx.x * blockDim.x + threadIdx.x;
    if (i < n) p[i] = 0;
}

// ---------------------------------------------------------------------------
// Histogram of destination nodes (edges + self loops).
// edge_index is INT32 per harness contract (integer -> const int*):
// row0 = src = ei[e], row1 = dst = ei[eraw + e].
// ---------------------------------------------------------------------------
__global__ void hist_kernel(const int* __restrict__ ei, int* __restrict__ counts,
                            int eraw, int etot, int n_nodes) {
    int e = blockIdx.x * blockDim.x + threadIdx.x;
    if (e >= etot) return;
    int dst = (e < eraw) ? ei[eraw + e] : (e - eraw);
    dst = min(max(dst, 0), n_nodes - 1);   // defensive: fail via absmax, not segfault
    atomicAdd(&counts[dst], 1);
}

// ---------------------------------------------------------------------------
// Single-block exclusive scan: indptr[0..n], cursor[i] = exclusive prefix
// ---------------------------------------------------------------------------
__global__ __launch_bounds__(1024) void scan_kernel(const int* __restrict__ counts,
                                                    int* __restrict__ indptr,
                                                    int* __restrict__ cursor, int n) {
    __shared__ int sdata[1024];
    __shared__ int s_carry;
    int t = threadIdx.x;
    if (t == 0) { s_carry = 0; indptr[0] = 0; }
    __syncthreads();
    for (int start = 0; start < n; start += 1024) {
        int i = start + t;
        int v = (i < n) ? counts[i] : 0;
        sdata[t] = v;
        __syncthreads();
        int val = v;
        for (int off = 1; off < 1024; off <<= 1) {
            int add = (t >= off) ? sdata[t - off] : 0;
            __syncthreads();
            val += add;
            sdata[t] = val;
            __syncthreads();
        }
        int carry = s_carry;
        if (i < n) {
            indptr[i + 1] = carry + val;
            cursor[i] = carry + val - v;   // exclusive
        }
        __syncthreads();
        if (t == 1023) s_carry = carry + val;
        __syncthreads();
    }
}

// ---------------------------------------------------------------------------
// Fill CSR src lists
// ---------------------------------------------------------------------------
__global__ void fill_kernel(const int* __restrict__ ei, int* __restrict__ cursor,
                            int* __restrict__ csr_src, int eraw, int etot, int n_nodes) {
    int e = blockIdx.x * blockDim.x + threadIdx.x;
    if (e >= etot) return;
    int s, d;
    if (e < eraw) { s = ei[e]; d = ei[eraw + e]; }
    else          { s = d = e - eraw; }
    s = min(max(s, 0), n_nodes - 1);       // defensive
    d = min(max(d, 0), n_nodes - 1);
    int pos = atomicAdd(&cursor[d], 1);
    pos = min(max(pos, 0), etot - 1);      // defensive
    csr_src[pos] = s;
}

// ---------------------------------------------------------------------------
// fp32 tiled GEMM: C[M,Nc] = A[M,K] @ B[K,Nc]
// 256 threads; each computes TM x TN. Requires (BM/TM)*(BN/TN) == 256,
// BM*BK and BK*BN multiples of 1024.
// ---------------------------------------------------------------------------
template <int BM, int BN, int BK, int TM, int TN>
__global__ __launch_bounds__(256) void gemm_kernel(const float* __restrict__ A,
                                                   const float* __restrict__ B,
                                                   float* __restrict__ C,
                                                   int M, int K, int Nc) {
    static_assert((BM / TM) * (BN / TN) == 256, "thread tiling");
    static_assert((BM * BK) % 1024 == 0 && (BK * BN) % 1024 == 0, "load tiling");
    constexpr int A_LOADS = BM * BK / 1024;
    constexpr int B_LOADS = BK * BN / 1024;
    __shared__ float As[BK][BM + 4];
    __shared__ float Bs[BK][BN + 4];
    int tid = threadIdx.x;
    int bm = blockIdx.x * BM;
    int bn = blockIdx.y * BN;
    int tx = tid % (BN / TN);
    int ty = tid / (BN / TN);
    float acc[TM][TN] = {};
    for (int k0 = 0; k0 < K; k0 += BK) {
#pragma unroll
        for (int i = 0; i < A_LOADS; i++) {
            int id = tid + i * 256;
            int r = id / (BK / 4);
            int cc = (id % (BK / 4)) * 4;
            int arow = min(bm + r, M - 1);
            float4 av = *(const float4*)&A[(size_t)arow * K + k0 + cc];
            As[cc + 0][r] = av.x; As[cc + 1][r] = av.y;
            As[cc + 2][r] = av.z; As[cc + 3][r] = av.w;
        }
#pragma unroll
        for (int i = 0; i < B_LOADS; i++) {
            int id = tid + i * 256;
            int r = id / (BN / 4);
            int cc = (id % (BN / 4)) * 4;
            float4 bv = *(const float4*)&B[(size_t)(k0 + r) * Nc + bn + cc];
            *(float4*)&Bs[r][cc] = bv;
        }
        __syncthreads();
#pragma unroll
        for (int k = 0; k < BK; k++) {
            float a[TM], b[TN];
#pragma unroll
            for (int i = 0; i < TM; i++) a[i] = As[k][ty * TM + i];
#pragma unroll
            for (int j = 0; j < TN; j++) b[j] = Bs[k][tx * TN + j];
#pragma unroll
            for (int i = 0; i < TM; i++)
#pragma unroll
                for (int j = 0; j < TN; j++) acc[i][j] += a[i] * b[j];
        }
        __syncthreads();
    }
#pragma unroll
    for (int i = 0; i < TM; i++) {
        int m = bm + ty * TM + i;
        if (m < M) {
#pragma unroll
            for (int j4 = 0; j4 < TN; j4 += 4) {
                float4 o = make_float4(acc[i][j4], acc[i][j4 + 1],
                                       acc[i][j4 + 2], acc[i][j4 + 3]);
                *(float4*)&C[(size_t)m * Nc + bn + tx * TN + j4] = o;
            }
        }
    }
}

// ---------------------------------------------------------------------------
// Attention coefficients: as_out[n*heads+h] = dot(h[n,h,:], a_src[h,:]) etc.
// One 64-lane wave per (node, head).
// ---------------------------------------------------------------------------
__global__ void alpha_kernel(const float* __restrict__ h, const float* __restrict__ a_src,
                             const float* __restrict__ a_dst, float* __restrict__ as_out,
                             float* __restrict__ ad_out, int n_nodes, int heads, int ch) {
    int lane = threadIdx.x & 63;
    int gw = blockIdx.x * (blockDim.x >> 6) + (threadIdx.x >> 6);
    if (gw >= n_nodes * heads) return;
    int n = gw / heads, hh = gw - n * heads;
    const float* hp = h + ((size_t)n * heads + hh) * ch;
    const float* sp = a_src + (size_t)hh * ch;
    const float* dp = a_dst + (size_t)hh * ch;
    float s = 0.f, d = 0.f;
    for (int c = lane; c < ch; c += 64) {
        float v = hp[c];
        s += v * sp[c];
        d += v * dp[c];
    }
#pragma unroll
    for (int off = 32; off; off >>= 1) {
        s += __shfl_xor(s, off);
        d += __shfl_xor(d, off);
    }
    if (lane == 0) { as_out[gw] = s; ad_out[gw] = d; }
}

// ---------------------------------------------------------------------------
// Layer-1 aggregation (+bias +ReLU): one block (256 thr) per dst node.
// Thread t handles channels 2t,2t+1 of 512; head = channel/128.
// Fused softmax: accumulate w and w*h, divide at end (shift-free softmax;
// e has std ~0.7 so exp() cannot overflow fp32).
// ---------------------------------------------------------------------------
__global__ __launch_bounds__(256) void agg1_kernel(const float* __restrict__ h1,
                                                   const float* __restrict__ as,
                                                   const float* __restrict__ ad,
                                                   const int* __restrict__ indptr,
                                                   const int* __restrict__ csr_src,
                                                   const float* __restrict__ b1,
                                                   float* __restrict__ out1) {
    int n = blockIdx.x;
    int t = threadIdx.x;
    int c = t * 2;
    int hh = c / HID;
    __shared__ int s_src[64];
    int p0 = indptr[n], p1 = indptr[n + 1];
    float accx = 0.f, accy = 0.f, den = 0.f;
    float adn = ad[(size_t)n * HEADS + hh];
    for (int base = p0; base < p1; base += 64) {
        int cnt = min(64, p1 - base);
        __syncthreads();
        if (t < cnt) s_src[t] = csr_src[base + t];
        __syncthreads();
        for (int j = 0; j < cnt; j++) {
            int s = s_src[j];
            float e = as[(size_t)s * HEADS + hh] + adn;
            e = e > 0.f ? e : NEG_SLOPE * e;
            float w = __expf(e);
            den += w;
            float2 hv = *(const float2*)&h1[(size_t)s * D1 + c];
            accx += w * hv.x;
            accy += w * hv.y;
        }
    }
    float inv = 1.0f / (den + 1e-16f);
    float ox = accx * inv + b1[c];
    float oy = accy * inv + b1[c + 1];
    ox = ox > 0.f ? ox : 0.f;   // ReLU between layers
    oy = oy > 0.f ? oy : 0.f;
    *(float2*)&out1[(size_t)n * D1 + c] = make_float2(ox, oy);
}

// ---------------------------------------------------------------------------
// Layer-2 aggregation (+bias): one wave per dst node, lane = channel (64).
// ---------------------------------------------------------------------------
__global__ __launch_bounds__(256) void agg2_kernel(const float* __restrict__ h2,
                                                   const float* __restrict__ as,
                                                   const float* __restrict__ ad,
                                                   const int* __restrict__ indptr,
                                                   const int* __restrict__ csr_src,
                                                   const float* __restrict__ b2,
                                                   float* __restrict__ out,
                                                   int n_nodes) {
    int lane = threadIdx.x & 63;
    int n = blockIdx.x * (blockDim.x >> 6) + (threadIdx.x >> 6);
    if (n >= n_nodes) return;
    int p0 = indptr[n], p1 = indptr[n + 1];
    float acc = 0.f, den = 0.f;
    float adn = ad[n];
    for (int p = p0; p < p1; p++) {
        int s = csr_src[p];
        float e = as[s] + adn;
        e = e > 0.f ? e : NEG_SLOPE * e;
        float w = __expf(e);
        den += w;
        acc += w * h2[(size_t)s * OUT_DIM + lane];
    }
    out[(size_t)n * OUT_DIM + lane] = acc / (den + 1e-16f) + b2[lane];
}

// ---------------------------------------------------------------------------
extern "C" void kernel_launch(void* const* d_in, const int* in_sizes, int n_in,
                              void* d_out, int out_size, void* d_ws, size_t ws_size,
                              hipStream_t stream) {
    const float* x      = (const float*)d_in[0];
    const int*   ei     = (const int*)d_in[1];     // harness: integer -> int32
    const float* W1     = (const float*)d_in[2];
    const float* a_src1 = (const float*)d_in[3];
    const float* a_dst1 = (const float*)d_in[4];
    const float* b1     = (const float*)d_in[5];
    const float* W2     = (const float*)d_in[6];
    const float* a_src2 = (const float*)d_in[7];
    const float* a_dst2 = (const float*)d_in[8];
    const float* b2     = (const float*)d_in[9];
    float* out = (float*)d_out;

    const int n    = in_sizes[0] / IN_DIM;   // 20000
    const int eraw = in_sizes[1] / 2;        // 320000
    const int etot = eraw + n;               // 340000

    // workspace layout (~92 MB total)
    char* base = (char*)d_ws;
    size_t off = 0;
    auto carve = [&](size_t bytes) { char* p = base + off; off = (off + bytes + 255) & ~(size_t)255; return p; };
    float* h1      = (float*)carve((size_t)n * D1 * 4);      // 40.96 MB
    float* out1    = (float*)carve((size_t)n * D1 * 4);      // 40.96 MB
    float* h2      = (float*)carve((size_t)n * OUT_DIM * 4); // 5.12 MB
    float* as1     = (float*)carve((size_t)n * HEADS * 4);
    float* ad1     = (float*)carve((size_t)n * HEADS * 4);
    float* as2     = (float*)carve((size_t)n * 4);
    float* ad2     = (float*)carve((size_t)n * 4);
    int*   counts  = (int*)carve((size_t)n * 4);
    int*   cursor  = (int*)carve((size_t)n * 4);
    int*   indptr  = (int*)carve((size_t)(n + 1) * 4);
    int*   csr_src = (int*)carve((size_t)etot * 4);
    (void)ws_size;

    // ---- CSR build ----
    zero_int_kernel<<<(n + 255) / 256, 256, 0, stream>>>(counts, n);
    hist_kernel<<<(etot + 255) / 256, 256, 0, stream>>>(ei, counts, eraw, etot, n);
    scan_kernel<<<1, 1024, 0, stream>>>(counts, indptr, cursor, n);
    fill_kernel<<<(etot + 255) / 256, 256, 0, stream>>>(ei, cursor, csr_src, eraw, etot, n);

    // ---- Layer 1: h1 = x @ W1 ----
    {
        dim3 grid((n + 127) / 128, D1 / 128);
        gemm_kernel<128, 128, 16, 8, 8><<<grid, 256, 0, stream>>>(x, W1, h1, n, IN_DIM, D1);
    }
    alpha_kernel<<<(n * HEADS + 3) / 4, 256, 0, stream>>>(h1, a_src1, a_dst1, as1, ad1, n, HEADS, HID);
    agg1_kernel<<<n, 256, 0, stream>>>(h1, as1, ad1, indptr, csr_src, b1, out1);

    // ---- Layer 2: h2 = out1 @ W2 ----
    {
        dim3 grid((n + 127) / 128, OUT_DIM / 64);
        gemm_kernel<128, 64, 16, 8, 4><<<grid, 256, 0, stream>>>(out1, W2, h2, n, D1, OUT_DIM);
    }
    alpha_kernel<<<(n + 3) / 4, 256, 0, stream>>>(h2, a_src2, a_dst2, as2, ad2, n, 1, OUT_DIM);
    agg2_kernel<<<(n + 3) / 4, 256, 0, stream>>>(h2, as2, ad2, indptr, csr_src, b2, out, n);
}

// Round 9
// 399.334 us; speedup vs baseline: 1.2536x; 1.2536x over previous
//
#include <hip/hip_runtime.h>
#include <hip/hip_bf16.h>

#define NEG_SLOPE 0.2f
#define IN_DIM 512
#define HID 128
#define HEADS 4
#define D1 (HEADS * HID)   // 512
#define OUT_DIM 64

typedef short bf8 __attribute__((ext_vector_type(8)));   // 8 bf16 (4 VGPR)
typedef short bf4 __attribute__((ext_vector_type(4)));   // 4 bf16
typedef float f32x16 __attribute__((ext_vector_type(16)));

// float -> bf16 split helpers (manual bit ops, RNE on lo)
__device__ inline short f2bf_rne(float x) {
    unsigned u = __float_as_uint(x);
    unsigned r = (u + 0x7FFFu + ((u >> 16) & 1u)) >> 16;
    return (short)r;
}
__device__ inline float bf2f(short b) {
    return __uint_as_float(((unsigned)(unsigned short)b) << 16);
}
__device__ inline void split_bf(float x, short& hi, short& lo) {
    hi = (short)(__float_as_uint(x) >> 16);        // truncate; residual captured by lo
    lo = f2bf_rne(x - bf2f(hi));
}

// ---------------------------------------------------------------------------
// Zero a word range
// ---------------------------------------------------------------------------
__global__ void zero_kernel(unsigned* __restrict__ p, int nwords) {
    int i = blockIdx.x * blockDim.x + threadIdx.x;
    if (i < nwords) p[i] = 0u;
}

// ---------------------------------------------------------------------------
// Histogram of destination nodes (edges + self loops). edge_index int32.
// ---------------------------------------------------------------------------
__global__ void hist_kernel(const int* __restrict__ ei, int* __restrict__ counts,
                            int eraw, int etot, int n_nodes) {
    int e = blockIdx.x * blockDim.x + threadIdx.x;
    if (e >= etot) return;
    int dst = (e < eraw) ? ei[eraw + e] : (e - eraw);
    dst = min(max(dst, 0), n_nodes - 1);
    atomicAdd(&counts[dst], 1);
}

// ---------------------------------------------------------------------------
// Single-block scan via per-thread serial chunk + wave shuffle scan.
// ---------------------------------------------------------------------------
__global__ __launch_bounds__(1024) void scan_kernel(const int* __restrict__ counts,
                                                    int* __restrict__ indptr,
                                                    int* __restrict__ cursor, int n) {
    __shared__ int wsum[16];
    int t = threadIdx.x;
    int per = (n + 1023) >> 10;
    int base = t * per;
    int mysum = 0;
    for (int j = 0; j < per; j++) {
        int i = base + j;
        if (i < n) mysum += counts[i];
    }
    int lane = t & 63, wid = t >> 6;
    int s = mysum;
#pragma unroll
    for (int d = 1; d < 64; d <<= 1) {
        int u = __shfl_up(s, d);
        if (lane >= d) s += u;
    }
    if (lane == 63) wsum[wid] = s;
    __syncthreads();
    if (wid == 0) {
        int v = (lane < 16) ? wsum[lane] : 0;
#pragma unroll
        for (int d = 1; d < 16; d <<= 1) {
            int u = __shfl_up(v, d);
            if (lane >= d) v += u;
        }
        if (lane < 16) wsum[lane] = v;
    }
    __syncthreads();
    int waveoff = (wid == 0) ? 0 : wsum[wid - 1];
    int run = waveoff + s - mysum;   // exclusive prefix of this thread's chunk
    for (int j = 0; j < per; j++) {
        int i = base + j;
        if (i < n) {
            int c = counts[i];
            cursor[i] = run;
            run += c;
            indptr[i + 1] = run;
        }
    }
    if (t == 0) indptr[0] = 0;
}

// ---------------------------------------------------------------------------
// Fill CSR src lists
// ---------------------------------------------------------------------------
__global__ void fill_kernel(const int* __restrict__ ei, int* __restrict__ cursor,
                            int* __restrict__ csr_src, int eraw, int etot, int n_nodes) {
    int e = blockIdx.x * blockDim.x + threadIdx.x;
    if (e >= etot) return;
    int s, d;
    if (e < eraw) { s = ei[e]; d = ei[eraw + e]; }
    else          { s = d = e - eraw; }
    s = min(max(s, 0), n_nodes - 1);
    d = min(max(d, 0), n_nodes - 1);
    int pos = atomicAdd(&cursor[d], 1);
    pos = min(max(pos, 0), etot - 1);
    csr_src[pos] = s;
}

// ---------------------------------------------------------------------------
// Split-bf16 MFMA GEMM: C[M,Nc] = A[M,K] @ B[K,Nc], fp32-accurate via
// Ah*Bh + Ah*Bl + Al*Bh (3x mfma_f32_32x32x16_bf16, fp32 accumulate).
// 256 threads = 4 waves (2x2), wave tile (BM/2)x(BN/2), frags 32x32.
// Optional fused alpha: as_out[m*AH + blockIdx.y] += dot(C_row, asrc_head).
// ---------------------------------------------------------------------------
template <int BM, int BN, int AH, bool FUSE>
__global__ __launch_bounds__(256) void gemm_mfma_kernel(
    const float* __restrict__ A, const float* __restrict__ Bmat,
    float* __restrict__ C, int M, int K, int Nc,
    const float* __restrict__ asrc, const float* __restrict__ adst,
    float* __restrict__ as_out, float* __restrict__ ad_out)
{
    constexpr int BK = 32;
    constexpr int KS = 40;            // padded stride in shorts (80B, 16B-aligned)
    constexpr int MR = BM / 64;       // 32x32 frags per wave in M
    constexpr int NR = BN / 64;
    __shared__ short Ah[BM][KS];
    __shared__ short Al[BM][KS];
    __shared__ short Bh[BN][KS];
    __shared__ short Bl[BN][KS];

    const int tid  = threadIdx.x;
    const int lane = tid & 63;
    const int wid  = tid >> 6;
    const int wr   = wid >> 1, wc = wid & 1;
    const int bm = blockIdx.x * BM;
    const int bn = blockIdx.y * BN;

    f32x16 acc[MR][NR] = {};

    const int arow0 = tid >> 3;            // A staging: row base (32 rows/pass)
    const int acol  = (tid & 7) << 2;      // float4 col within BK
    const int bnn0  = tid & 63;            // B staging: n within 64 block
    const int bkc   = (tid >> 6) << 3;     // 8-k chunk per wave

    for (int k0 = 0; k0 < K; k0 += BK) {
        // ---- stage A (fp32 -> bf16 hi/lo) ----
#pragma unroll
        for (int i = 0; i < BM / 32; i++) {
            int r = arow0 + i * 32;
            int gr = bm + r; gr = gr < M ? gr : M - 1;
            float4 v = *(const float4*)&A[(size_t)gr * K + k0 + acol];
            float xs[4] = {v.x, v.y, v.z, v.w};
            bf4 hi, lo;
#pragma unroll
            for (int e = 0; e < 4; e++) {
                short h, l;
                split_bf(xs[e], h, l);
                hi[e] = h; lo[e] = l;
            }
            *(bf4*)&Ah[r][acol] = hi;
            *(bf4*)&Al[r][acol] = lo;
        }
        // ---- stage B transposed (fp32 row-major -> bf16 hi/lo [n][k]) ----
#pragma unroll
        for (int i = 0; i < BN / 64; i++) {
            int nn = bnn0 + i * 64;
            bf8 hi, lo;
#pragma unroll
            for (int e = 0; e < 8; e++) {
                float x = Bmat[(size_t)(k0 + bkc + e) * Nc + bn + nn];
                short h, l;
                split_bf(x, h, l);
                hi[e] = h; lo[e] = l;
            }
            *(bf8*)&Bh[nn][bkc] = hi;
            *(bf8*)&Bl[nn][bkc] = lo;
        }
        __syncthreads();
        // ---- MFMA: two K=16 chunks per BK=32 tile ----
#pragma unroll
        for (int kk = 0; kk < 2; kk++) {
            const int ki = kk * 16 + (lane >> 5) * 8;
            bf8 afh[MR], afl[MR], bfh[NR], bfl[NR];
#pragma unroll
            for (int mr = 0; mr < MR; mr++) {
                int r = wr * (BM / 2) + mr * 32 + (lane & 31);
                afh[mr] = *(const bf8*)&Ah[r][ki];
                afl[mr] = *(const bf8*)&Al[r][ki];
            }
#pragma unroll
            for (int nr = 0; nr < NR; nr++) {
                int cn = wc * (BN / 2) + nr * 32 + (lane & 31);
                bfh[nr] = *(const bf8*)&Bh[cn][ki];
                bfl[nr] = *(const bf8*)&Bl[cn][ki];
            }
#pragma unroll
            for (int mr = 0; mr < MR; mr++)
#pragma unroll
                for (int nr = 0; nr < NR; nr++) {
                    acc[mr][nr] = __builtin_amdgcn_mfma_f32_32x32x16_bf16(afh[mr], bfh[nr], acc[mr][nr], 0, 0, 0);
                    acc[mr][nr] = __builtin_amdgcn_mfma_f32_32x32x16_bf16(afh[mr], bfl[nr], acc[mr][nr], 0, 0, 0);
                    acc[mr][nr] = __builtin_amdgcn_mfma_f32_32x32x16_bf16(afl[mr], bfh[nr], acc[mr][nr], 0, 0, 0);
                }
        }
        __syncthreads();
    }

    // ---- C write: 32x32 frag C/D map: col = lane&31, row = (reg&3)+8*(reg>>2)+4*(lane>>5)
    const int hl = lane >> 5;
    const int cl = lane & 31;
#pragma unroll
    for (int mr = 0; mr < MR; mr++)
#pragma unroll
        for (int reg = 0; reg < 16; reg++) {
            int rloc = (reg & 3) + 8 * (reg >> 2) + 4 * hl;
            int m = bm + wr * (BM / 2) + mr * 32 + rloc;
            if (m < M) {
#pragma unroll
                for (int nr = 0; nr < NR; nr++) {
                    int cn = bn + wc * (BN / 2) + nr * 32 + cl;
                    C[(size_t)m * Nc + cn] = acc[mr][nr][reg];
                }
            }
        }

    if constexpr (FUSE) {
        // fused attention-coefficient dots over this block's BN channels
        const float* asp = asrc + (size_t)blockIdx.y * BN;
        const float* adp = adst + (size_t)blockIdx.y * BN;
#pragma unroll
        for (int mr = 0; mr < MR; mr++)
#pragma unroll
            for (int reg = 0; reg < 16; reg++) {
                float s = 0.f, d = 0.f;
#pragma unroll
                for (int nr = 0; nr < NR; nr++) {
                    int ch = wc * (BN / 2) + nr * 32 + cl;
                    float v = acc[mr][nr][reg];
                    s += v * asp[ch];
                    d += v * adp[ch];
                }
#pragma unroll
                for (int off = 16; off; off >>= 1) {
                    s += __shfl_xor(s, off);
                    d += __shfl_xor(d, off);
                }
                if (cl == 0) {
                    int rloc = (reg & 3) + 8 * (reg >> 2) + 4 * hl;
                    int m = bm + wr * (BM / 2) + mr * 32 + rloc;
                    if (m < M) {
                        atomicAdd(&as_out[(size_t)m * AH + blockIdx.y], s);
                        atomicAdd(&ad_out[(size_t)m * AH + blockIdx.y], d);
                    }
                }
            }
    }
}

// ---------------------------------------------------------------------------
// Layer-1 aggregation (+bias +ReLU): one block (256 thr) per dst node.
// Edge weights computed ONCE per edge during staging (all 4 heads), stored in
// LDS; inner loop is broadcast LDS read + coalesced h1 gather + FMA.
// ---------------------------------------------------------------------------
__global__ __launch_bounds__(256) void agg1_kernel(const float* __restrict__ h1,
                                                   const float* __restrict__ as,
                                                   const float* __restrict__ ad,
                                                   const int* __restrict__ indptr,
                                                   const int* __restrict__ csr_src,
                                                   const float* __restrict__ b1,
                                                   float* __restrict__ out1) {
    int n = blockIdx.x;
    int t = threadIdx.x;
    int c = t * 2;
    int hh = t >> 6;               // c / HID
    __shared__ int   s_src[64];
    __shared__ float s_w[64][4];
    int p0 = indptr[n], p1 = indptr[n + 1];
    float accx = 0.f, accy = 0.f, den = 0.f;
    for (int base = p0; base < p1; base += 64) {
        int cnt = min(64, p1 - base);
        __syncthreads();
        if (t < cnt) {
            int s = csr_src[base + t];
            s_src[t] = s;
            float4 av = *(const float4*)&as[(size_t)s * HEADS];
            float4 dv = *(const float4*)&ad[(size_t)n * HEADS];
            float e0 = av.x + dv.x, e1 = av.y + dv.y, e2 = av.z + dv.z, e3 = av.w + dv.w;
            e0 = e0 > 0.f ? e0 : NEG_SLOPE * e0;
            e1 = e1 > 0.f ? e1 : NEG_SLOPE * e1;
            e2 = e2 > 0.f ? e2 : NEG_SLOPE * e2;
            e3 = e3 > 0.f ? e3 : NEG_SLOPE * e3;
            s_w[t][0] = __expf(e0);
            s_w[t][1] = __expf(e1);
            s_w[t][2] = __expf(e2);
            s_w[t][3] = __expf(e3);
        }
        __syncthreads();
        for (int j = 0; j < cnt; j++) {
            int s = s_src[j];
            float w = s_w[j][hh];
            den += w;
            float2 hv = *(const float2*)&h1[(size_t)s * D1 + c];
            accx += w * hv.x;
            accy += w * hv.y;
        }
    }
    float inv = 1.0f / (den + 1e-16f);
    float ox = accx * inv + b1[c];
    float oy = accy * inv + b1[c + 1];
    ox = ox > 0.f ? ox : 0.f;
    oy = oy > 0.f ? oy : 0.f;
    *(float2*)&out1[(size_t)n * D1 + c] = make_float2(ox, oy);
}

// ---------------------------------------------------------------------------
// Layer-2 aggregation (+bias): one wave per dst node, lane = channel (64).
// ---------------------------------------------------------------------------
__global__ __launch_bounds__(256) void agg2_kernel(const float* __restrict__ h2,
                                                   const float* __restrict__ as,
                                                   const float* __restrict__ ad,
                                                   const int* __restrict__ indptr,
                                                   const int* __restrict__ csr_src,
                                                   const float* __restrict__ b2,
                                                   float* __restrict__ out,
                                                   int n_nodes) {
    int lane = threadIdx.x & 63;
    int n = blockIdx.x * (blockDim.x >> 6) + (threadIdx.x >> 6);
    if (n >= n_nodes) return;
    int p0 = indptr[n], p1 = indptr[n + 1];
    float acc = 0.f, den = 0.f;
    float adn = ad[n];
    for (int p = p0; p < p1; p++) {
        int s = csr_src[p];
        float e = as[s] + adn;
        e = e > 0.f ? e : NEG_SLOPE * e;
        float w = __expf(e);
        den += w;
        acc += w * h2[(size_t)s * OUT_DIM + lane];
    }
    out[(size_t)n * OUT_DIM + lane] = acc / (den + 1e-16f) + b2[lane];
}

// ---------------------------------------------------------------------------
extern "C" void kernel_launch(void* const* d_in, const int* in_sizes, int n_in,
                              void* d_out, int out_size, void* d_ws, size_t ws_size,
                              hipStream_t stream) {
    const float* x      = (const float*)d_in[0];
    const int*   ei     = (const int*)d_in[1];
    const float* W1     = (const float*)d_in[2];
    const float* a_src1 = (const float*)d_in[3];
    const float* a_dst1 = (const float*)d_in[4];
    const float* b1     = (const float*)d_in[5];
    const float* W2     = (const float*)d_in[6];
    const float* a_src2 = (const float*)d_in[7];
    const float* a_dst2 = (const float*)d_in[8];
    const float* b2     = (const float*)d_in[9];
    float* out = (float*)d_out;

    const int n    = in_sizes[0] / IN_DIM;   // 20000
    const int eraw = in_sizes[1] / 2;        // 320000
    const int etot = eraw + n;               // 340000

    // workspace layout (~90 MB)
    char* base = (char*)d_ws;
    size_t off = 0;
    auto carve = [&](size_t bytes) { char* p = base + off; off = (off + bytes + 255) & ~(size_t)255; return p; };
    float* h1      = (float*)carve((size_t)n * D1 * 4);
    float* out1    = (float*)carve((size_t)n * D1 * 4);
    float* h2      = (float*)carve((size_t)n * OUT_DIM * 4);
    // contiguous zero region: counts + alpha accumulators
    int*   counts  = (int*)carve((size_t)n * 4);
    float* as1     = (float*)carve((size_t)n * HEADS * 4);
    float* ad1     = (float*)carve((size_t)n * HEADS * 4);
    float* as2     = (float*)carve((size_t)n * 4);
    float* ad2     = (float*)carve((size_t)n * 4);
    char*  zend    = base + off;
    int*   cursor  = (int*)carve((size_t)n * 4);
    int*   indptr  = (int*)carve((size_t)(n + 1) * 4);
    int*   csr_src = (int*)carve((size_t)etot * 4);
    (void)ws_size;

    // ---- init + CSR build ----
    int zwords = (int)((zend - (char*)counts) / 4);
    zero_kernel<<<(zwords + 255) / 256, 256, 0, stream>>>((unsigned*)counts, zwords);
    hist_kernel<<<(etot + 255) / 256, 256, 0, stream>>>(ei, counts, eraw, etot, n);
    scan_kernel<<<1, 1024, 0, stream>>>(counts, indptr, cursor, n);
    fill_kernel<<<(etot + 255) / 256, 256, 0, stream>>>(ei, cursor, csr_src, eraw, etot, n);

    // ---- Layer 1: h1 = x @ W1  (+ fused alpha dots) ----
    {
        dim3 grid((n + 127) / 128, D1 / 128);   // blockIdx.y == head
        gemm_mfma_kernel<128, 128, HEADS, true><<<grid, 256, 0, stream>>>(
            x, W1, h1, n, IN_DIM, D1, a_src1, a_dst1, as1, ad1);
    }
    agg1_kernel<<<n, 256, 0, stream>>>(h1, as1, ad1, indptr, csr_src, b1, out1);

    // ---- Layer 2: h2 = out1 @ W2  (+ fused alpha dots) ----
    {
        dim3 grid((n + 63) / 64, 1);
        gemm_mfma_kernel<64, 64, 1, true><<<grid, 256, 0, stream>>>(
            out1, W2, h2, n, D1, OUT_DIM, a_src2, a_dst2, as2, ad2);
    }
    agg2_kernel<<<(n + 3) / 4, 256, 0, stream>>>(h2, as2, ad2, indptr, csr_src, b2, out, n);
}

// Round 10
// 387.163 us; speedup vs baseline: 1.2930x; 1.0314x over previous
//
#include <hip/hip_runtime.h>
#include <hip/hip_bf16.h>

#define NEG_SLOPE 0.2f
#define IN_DIM 512
#define HID 128
#define HEADS 4
#define D1 (HEADS * HID)   // 512
#define OUT_DIM 64

typedef short bf8 __attribute__((ext_vector_type(8)));   // 8 bf16 (4 VGPR)
typedef short bf4 __attribute__((ext_vector_type(4)));   // 4 bf16
typedef float f32x16 __attribute__((ext_vector_type(16)));

// float -> bf16 split helpers (manual bit ops, RNE on lo)
__device__ inline short f2bf_rne(float x) {
    unsigned u = __float_as_uint(x);
    unsigned r = (u + 0x7FFFu + ((u >> 16) & 1u)) >> 16;
    return (short)r;
}
__device__ inline float bf2f(short b) {
    return __uint_as_float(((unsigned)(unsigned short)b) << 16);
}
__device__ inline void split_bf(float x, short& hi, short& lo) {
    hi = (short)(__float_as_uint(x) >> 16);        // truncate; residual captured by lo
    lo = f2bf_rne(x - bf2f(hi));
}

// ---------------------------------------------------------------------------
// Zero a word range
// ---------------------------------------------------------------------------
__global__ void zero_kernel(unsigned* __restrict__ p, int nwords) {
    int i = blockIdx.x * blockDim.x + threadIdx.x;
    if (i < nwords) p[i] = 0u;
}

// ---------------------------------------------------------------------------
// Histogram of destination nodes (edges + self loops). edge_index int32.
// ---------------------------------------------------------------------------
__global__ void hist_kernel(const int* __restrict__ ei, int* __restrict__ counts,
                            int eraw, int etot, int n_nodes) {
    int e = blockIdx.x * blockDim.x + threadIdx.x;
    if (e >= etot) return;
    int dst = (e < eraw) ? ei[eraw + e] : (e - eraw);
    dst = min(max(dst, 0), n_nodes - 1);
    atomicAdd(&counts[dst], 1);
}

// ---------------------------------------------------------------------------
// Single-block scan via per-thread serial chunk + wave shuffle scan.
// ---------------------------------------------------------------------------
__global__ __launch_bounds__(1024) void scan_kernel(const int* __restrict__ counts,
                                                    int* __restrict__ indptr,
                                                    int* __restrict__ cursor, int n) {
    __shared__ int wsum[16];
    int t = threadIdx.x;
    int per = (n + 1023) >> 10;
    int base = t * per;
    int mysum = 0;
    for (int j = 0; j < per; j++) {
        int i = base + j;
        if (i < n) mysum += counts[i];
    }
    int lane = t & 63, wid = t >> 6;
    int s = mysum;
#pragma unroll
    for (int d = 1; d < 64; d <<= 1) {
        int u = __shfl_up(s, d);
        if (lane >= d) s += u;
    }
    if (lane == 63) wsum[wid] = s;
    __syncthreads();
    if (wid == 0) {
        int v = (lane < 16) ? wsum[lane] : 0;
#pragma unroll
        for (int d = 1; d < 16; d <<= 1) {
            int u = __shfl_up(v, d);
            if (lane >= d) v += u;
        }
        if (lane < 16) wsum[lane] = v;
    }
    __syncthreads();
    int waveoff = (wid == 0) ? 0 : wsum[wid - 1];
    int run = waveoff + s - mysum;   // exclusive prefix of this thread's chunk
    for (int j = 0; j < per; j++) {
        int i = base + j;
        if (i < n) {
            int c = counts[i];
            cursor[i] = run;
            run += c;
            indptr[i + 1] = run;
        }
    }
    if (t == 0) indptr[0] = 0;
}

// ---------------------------------------------------------------------------
// Fill CSR src lists
// ---------------------------------------------------------------------------
__global__ void fill_kernel(const int* __restrict__ ei, int* __restrict__ cursor,
                            int* __restrict__ csr_src, int eraw, int etot, int n_nodes) {
    int e = blockIdx.x * blockDim.x + threadIdx.x;
    if (e >= etot) return;
    int s, d;
    if (e < eraw) { s = ei[e]; d = ei[eraw + e]; }
    else          { s = d = e - eraw; }
    s = min(max(s, 0), n_nodes - 1);
    d = min(max(d, 0), n_nodes - 1);
    int pos = atomicAdd(&cursor[d], 1);
    pos = min(max(pos, 0), etot - 1);
    csr_src[pos] = s;
}

// ---------------------------------------------------------------------------
// Split-bf16 MFMA GEMM: C[M,Nc] = A[M,K] @ B[K,Nc], fp32-accurate via
// Ah*Bh + Ah*Bl + Al*Bh (3x mfma_f32_32x32x16_bf16, fp32 accumulate).
// 256 threads = 4 waves (2x2), wave tile (BM/2)x(BN/2), frags 32x32.
// Optional fused alpha: as_out[m*AH + blockIdx.y] += dot(C_row, asrc_head).
// ---------------------------------------------------------------------------
template <int BM, int BN, int AH, bool FUSE>
__global__ __launch_bounds__(256) void gemm_mfma_kernel(
    const float* __restrict__ A, const float* __restrict__ Bmat,
    float* __restrict__ C, int M, int K, int Nc,
    const float* __restrict__ asrc, const float* __restrict__ adst,
    float* __restrict__ as_out, float* __restrict__ ad_out)
{
    constexpr int BK = 32;
    constexpr int KS = 40;            // padded stride in shorts (80B, 16B-aligned)
    constexpr int MR = BM / 64;       // 32x32 frags per wave in M
    constexpr int NR = BN / 64;
    __shared__ short Ah[BM][KS];
    __shared__ short Al[BM][KS];
    __shared__ short Bh[BN][KS];
    __shared__ short Bl[BN][KS];

    const int tid  = threadIdx.x;
    const int lane = tid & 63;
    const int wid  = tid >> 6;
    const int wr   = wid >> 1, wc = wid & 1;
    const int bm = blockIdx.x * BM;
    const int bn = blockIdx.y * BN;

    f32x16 acc[MR][NR] = {};

    const int arow0 = tid >> 3;            // A staging: row base (32 rows/pass)
    const int acol  = (tid & 7) << 2;      // float4 col within BK
    const int bnn0  = tid & 63;            // B staging: n within 64 block
    const int bkc   = (tid >> 6) << 3;     // 8-k chunk per wave

    for (int k0 = 0; k0 < K; k0 += BK) {
        // ---- stage A (fp32 -> bf16 hi/lo) ----
#pragma unroll
        for (int i = 0; i < BM / 32; i++) {
            int r = arow0 + i * 32;
            int gr = bm + r; gr = gr < M ? gr : M - 1;
            float4 v = *(const float4*)&A[(size_t)gr * K + k0 + acol];
            float xs[4] = {v.x, v.y, v.z, v.w};
            bf4 hi, lo;
#pragma unroll
            for (int e = 0; e < 4; e++) {
                short h, l;
                split_bf(xs[e], h, l);
                hi[e] = h; lo[e] = l;
            }
            *(bf4*)&Ah[r][acol] = hi;
            *(bf4*)&Al[r][acol] = lo;
        }
        // ---- stage B transposed (fp32 row-major -> bf16 hi/lo [n][k]) ----
#pragma unroll
        for (int i = 0; i < BN / 64; i++) {
            int nn = bnn0 + i * 64;
            bf8 hi, lo;
#pragma unroll
            for (int e = 0; e < 8; e++) {
                float x = Bmat[(size_t)(k0 + bkc + e) * Nc + bn + nn];
                short h, l;
                split_bf(x, h, l);
                hi[e] = h; lo[e] = l;
            }
            *(bf8*)&Bh[nn][bkc] = hi;
            *(bf8*)&Bl[nn][bkc] = lo;
        }
        __syncthreads();
        // ---- MFMA: two K=16 chunks per BK=32 tile ----
#pragma unroll
        for (int kk = 0; kk < 2; kk++) {
            const int ki = kk * 16 + (lane >> 5) * 8;
            bf8 afh[MR], afl[MR], bfh[NR], bfl[NR];
#pragma unroll
            for (int mr = 0; mr < MR; mr++) {
                int r = wr * (BM / 2) + mr * 32 + (lane & 31);
                afh[mr] = *(const bf8*)&Ah[r][ki];
                afl[mr] = *(const bf8*)&Al[r][ki];
            }
#pragma unroll
            for (int nr = 0; nr < NR; nr++) {
                int cn = wc * (BN / 2) + nr * 32 + (lane & 31);
                bfh[nr] = *(const bf8*)&Bh[cn][ki];
                bfl[nr] = *(const bf8*)&Bl[cn][ki];
            }
#pragma unroll
            for (int mr = 0; mr < MR; mr++)
#pragma unroll
                for (int nr = 0; nr < NR; nr++) {
                    acc[mr][nr] = __builtin_amdgcn_mfma_f32_32x32x16_bf16(afh[mr], bfh[nr], acc[mr][nr], 0, 0, 0);
                    acc[mr][nr] = __builtin_amdgcn_mfma_f32_32x32x16_bf16(afh[mr], bfl[nr], acc[mr][nr], 0, 0, 0);
                    acc[mr][nr] = __builtin_amdgcn_mfma_f32_32x32x16_bf16(afl[mr], bfh[nr], acc[mr][nr], 0, 0, 0);
                }
        }
        __syncthreads();
    }

    // ---- C write: 32x32 frag C/D map: col = lane&31, row = (reg&3)+8*(reg>>2)+4*(lane>>5)
    const int hl = lane >> 5;
    const int cl = lane & 31;
#pragma unroll
    for (int mr = 0; mr < MR; mr++)
#pragma unroll
        for (int reg = 0; reg < 16; reg++) {
            int rloc = (reg & 3) + 8 * (reg >> 2) + 4 * hl;
            int m = bm + wr * (BM / 2) + mr * 32 + rloc;
            if (m < M) {
#pragma unroll
                for (int nr = 0; nr < NR; nr++) {
                    int cn = bn + wc * (BN / 2) + nr * 32 + cl;
                    C[(size_t)m * Nc + cn] = acc[mr][nr][reg];
                }
            }
        }

    if constexpr (FUSE) {
        // fused attention-coefficient dots over this block's BN channels
        const float* asp = asrc + (size_t)blockIdx.y * BN;
        const float* adp = adst + (size_t)blockIdx.y * BN;
#pragma unroll
        for (int mr = 0; mr < MR; mr++)
#pragma unroll
            for (int reg = 0; reg < 16; reg++) {
                float s = 0.f, d = 0.f;
#pragma unroll
                for (int nr = 0; nr < NR; nr++) {
                    int ch = wc * (BN / 2) + nr * 32 + cl;
                    float v = acc[mr][nr][reg];
                    s += v * asp[ch];
                    d += v * adp[ch];
                }
#pragma unroll
                for (int off = 16; off; off >>= 1) {
                    s += __shfl_xor(s, off);
                    d += __shfl_xor(d, off);
                }
                if (cl == 0) {
                    int rloc = (reg & 3) + 8 * (reg >> 2) + 4 * hl;
                    int m = bm + wr * (BM / 2) + mr * 32 + rloc;
                    if (m < M) {
                        atomicAdd(&as_out[(size_t)m * AH + blockIdx.y], s);
                        atomicAdd(&ad_out[(size_t)m * AH + blockIdx.y], d);
                    }
                }
            }
    }
}

// ---------------------------------------------------------------------------
// Layer-1 aggregation (+bias +ReLU): one block (256 thr) per dst node.
// Edge weights staged once per 64-edge tile in LDS. Inner loop: half-block
// parity q handles edges j2+q with float4 (16B/lane) h1 loads -> 2 edges in
// flight, 2x memory-level parallelism. Parity partials combined via LDS.
// ---------------------------------------------------------------------------
__global__ __launch_bounds__(256) void agg1_kernel(const float* __restrict__ h1,
                                                   const float* __restrict__ as,
                                                   const float* __restrict__ ad,
                                                   const int* __restrict__ indptr,
                                                   const int* __restrict__ csr_src,
                                                   const float* __restrict__ b1,
                                                   float* __restrict__ out1) {
    int n = blockIdx.x;
    int t = threadIdx.x;
    int q = t >> 7;                 // edge parity for this half-block
    int u = t & 127;                // channel quad: channels 4u..4u+3
    int c = u << 2;
    int hh = u >> 5;                // head = c/128
    __shared__ int    s_src[64];
    __shared__ float  s_w[64][4];
    __shared__ float4 s_pacc[128];
    __shared__ float  s_pden[128];
    int p0 = indptr[n], p1 = indptr[n + 1];
    float4 acc = make_float4(0.f, 0.f, 0.f, 0.f);
    float den = 0.f;
    for (int base = p0; base < p1; base += 64) {
        int cnt = min(64, p1 - base);
        __syncthreads();
        if (t < cnt) {
            int s = csr_src[base + t];
            s_src[t] = s;
            float4 av = *(const float4*)&as[(size_t)s * HEADS];
            float4 dv = *(const float4*)&ad[(size_t)n * HEADS];
            float e0 = av.x + dv.x, e1 = av.y + dv.y, e2 = av.z + dv.z, e3 = av.w + dv.w;
            e0 = e0 > 0.f ? e0 : NEG_SLOPE * e0;
            e1 = e1 > 0.f ? e1 : NEG_SLOPE * e1;
            e2 = e2 > 0.f ? e2 : NEG_SLOPE * e2;
            e3 = e3 > 0.f ? e3 : NEG_SLOPE * e3;
            s_w[t][0] = __expf(e0);
            s_w[t][1] = __expf(e1);
            s_w[t][2] = __expf(e2);
            s_w[t][3] = __expf(e3);
        }
        __syncthreads();
        for (int j2 = 0; j2 < cnt; j2 += 2) {
            int j = j2 + q;
            if (j < cnt) {
                int s = s_src[j];
                float w = s_w[j][hh];
                float4 hv = *(const float4*)&h1[(size_t)s * D1 + c];
                acc.x += w * hv.x; acc.y += w * hv.y;
                acc.z += w * hv.z; acc.w += w * hv.w;
                den += w;
            }
        }
    }
    // combine the two parity partials
    __syncthreads();
    if (q == 1) { s_pacc[u] = acc; s_pden[u] = den; }
    __syncthreads();
    if (q == 0) {
        float4 a2 = s_pacc[u];
        acc.x += a2.x; acc.y += a2.y; acc.z += a2.z; acc.w += a2.w;
        den += s_pden[u];
        float inv = 1.0f / (den + 1e-16f);
        float4 bv = *(const float4*)&b1[c];
        float4 o;
        o.x = fmaxf(acc.x * inv + bv.x, 0.f);
        o.y = fmaxf(acc.y * inv + bv.y, 0.f);
        o.z = fmaxf(acc.z * inv + bv.z, 0.f);
        o.w = fmaxf(acc.w * inv + bv.w, 0.f);
        *(float4*)&out1[(size_t)n * D1 + c] = o;
    }
}

// ---------------------------------------------------------------------------
// Layer-2 aggregation (+bias): one wave per dst node. Half-wave parity eq
// handles edges p2+eq; lanes 0..31 cover the 64 channels via float2 (8B).
// Partials combined with __shfl_xor(32).
// ---------------------------------------------------------------------------
__global__ __launch_bounds__(256) void agg2_kernel(const float* __restrict__ h2,
                                                   const float* __restrict__ as,
                                                   const float* __restrict__ ad,
                                                   const int* __restrict__ indptr,
                                                   const int* __restrict__ csr_src,
                                                   const float* __restrict__ b2,
                                                   float* __restrict__ out,
                                                   int n_nodes) {
    int lane = threadIdx.x & 63;
    int n = blockIdx.x * (blockDim.x >> 6) + (threadIdx.x >> 6);
    if (n >= n_nodes) return;
    int eq = lane >> 5;            // edge parity for this half-wave
    int c  = (lane & 31) * 2;      // channels c, c+1
    int p0 = indptr[n], p1 = indptr[n + 1];
    float accx = 0.f, accy = 0.f, den = 0.f;
    float adn = ad[n];
    for (int p2 = p0; p2 < p1; p2 += 2) {
        int p = p2 + eq;
        if (p < p1) {
            int s = csr_src[p];
            float e = as[s] + adn;
            e = e > 0.f ? e : NEG_SLOPE * e;
            float w = __expf(e);
            den += w;
            float2 hv = *(const float2*)&h2[(size_t)s * OUT_DIM + c];
            accx += w * hv.x;
            accy += w * hv.y;
        }
    }
    accx += __shfl_xor(accx, 32);
    accy += __shfl_xor(accy, 32);
    den  += __shfl_xor(den, 32);
    if (eq == 0) {
        float inv = 1.0f / (den + 1e-16f);
        float2 o = make_float2(accx * inv + b2[c], accy * inv + b2[c + 1]);
        *(float2*)&out[(size_t)n * OUT_DIM + c] = o;
    }
}

// ---------------------------------------------------------------------------
extern "C" void kernel_launch(void* const* d_in, const int* in_sizes, int n_in,
                              void* d_out, int out_size, void* d_ws, size_t ws_size,
                              hipStream_t stream) {
    const float* x      = (const float*)d_in[0];
    const int*   ei     = (const int*)d_in[1];
    const float* W1     = (const float*)d_in[2];
    const float* a_src1 = (const float*)d_in[3];
    const float* a_dst1 = (const float*)d_in[4];
    const float* b1     = (const float*)d_in[5];
    const float* W2     = (const float*)d_in[6];
    const float* a_src2 = (const float*)d_in[7];
    const float* a_dst2 = (const float*)d_in[8];
    const float* b2     = (const float*)d_in[9];
    float* out = (float*)d_out;

    const int n    = in_sizes[0] / IN_DIM;   // 20000
    const int eraw = in_sizes[1] / 2;        // 320000
    const int etot = eraw + n;               // 340000

    // workspace layout (~90 MB)
    char* base = (char*)d_ws;
    size_t off = 0;
    auto carve = [&](size_t bytes) { char* p = base + off; off = (off + bytes + 255) & ~(size_t)255; return p; };
    float* h1      = (float*)carve((size_t)n * D1 * 4);
    float* out1    = (float*)carve((size_t)n * D1 * 4);
    float* h2      = (float*)carve((size_t)n * OUT_DIM * 4);
    // contiguous zero region: counts + alpha accumulators
    int*   counts  = (int*)carve((size_t)n * 4);
    float* as1     = (float*)carve((size_t)n * HEADS * 4);
    float* ad1     = (float*)carve((size_t)n * HEADS * 4);
    float* as2     = (float*)carve((size_t)n * 4);
    float* ad2     = (float*)carve((size_t)n * 4);
    char*  zend    = base + off;
    int*   cursor  = (int*)carve((size_t)n * 4);
    int*   indptr  = (int*)carve((size_t)(n + 1) * 4);
    int*   csr_src = (int*)carve((size_t)etot * 4);
    (void)ws_size;

    // ---- init + CSR build ----
    int zwords = (int)((zend - (char*)counts) / 4);
    zero_kernel<<<(zwords + 255) / 256, 256, 0, stream>>>((unsigned*)counts, zwords);
    hist_kernel<<<(etot + 255) / 256, 256, 0, stream>>>(ei, counts, eraw, etot, n);
    scan_kernel<<<1, 1024, 0, stream>>>(counts, indptr, cursor, n);
    fill_kernel<<<(etot + 255) / 256, 256, 0, stream>>>(ei, cursor, csr_src, eraw, etot, n);

    // ---- Layer 1: h1 = x @ W1  (+ fused alpha dots) ----
    {
        dim3 grid((n + 127) / 128, D1 / 128);   // blockIdx.y == head
        gemm_mfma_kernel<128, 128, HEADS, true><<<grid, 256, 0, stream>>>(
            x, W1, h1, n, IN_DIM, D1, a_src1, a_dst1, as1, ad1);
    }
    agg1_kernel<<<n, 256, 0, stream>>>(h1, as1, ad1, indptr, csr_src, b1, out1);

    // ---- Layer 2: h2 = out1 @ W2  (+ fused alpha dots) ----
    {
        dim3 grid((n + 63) / 64, 1);
        gemm_mfma_kernel<64, 64, 1, true><<<grid, 256, 0, stream>>>(
            out1, W2, h2, n, D1, OUT_DIM, a_src2, a_dst2, as2, ad2);
    }
    agg2_kernel<<<(n + 3) / 4, 256, 0, stream>>>(h2, as2, ad2, indptr, csr_src, b2, out, n);
}

// Round 12
// 324.796 us; speedup vs baseline: 1.5413x; 1.1920x over previous
//
#include <hip/hip_runtime.h>
#include <hip/hip_bf16.h>

#define NEG_SLOPE 0.2f
#define IN_DIM 512
#define HID 128
#define HEADS 4
#define D1 (HEADS * HID)   // 512
#define OUT_DIM 64

typedef short bf8 __attribute__((ext_vector_type(8)));   // 8 bf16 (4 VGPR)
typedef short bf4 __attribute__((ext_vector_type(4)));   // 4 bf16
typedef unsigned short u16x8 __attribute__((ext_vector_type(8)));
typedef float f32x16 __attribute__((ext_vector_type(16)));

// float -> bf16 split helpers (manual bit ops, RNE on lo)
__device__ inline unsigned short f2bf_rne(float x) {
    unsigned u = __float_as_uint(x);
    unsigned r = (u + 0x7FFFu + ((u >> 16) & 1u)) >> 16;
    return (unsigned short)r;
}
__device__ inline float bf2f(unsigned short b) {
    return __uint_as_float(((unsigned)b) << 16);
}
__device__ inline void split_bf(float x, short& hi, short& lo) {
    hi = (short)(__float_as_uint(x) >> 16);        // truncate; residual captured by lo
    lo = (short)f2bf_rne(x - bf2f((unsigned short)(__float_as_uint(x) >> 16)));
}

// ---------------------------------------------------------------------------
// Zero a word range
// ---------------------------------------------------------------------------
__global__ void zero_kernel(unsigned* __restrict__ p, int nwords) {
    int i = blockIdx.x * blockDim.x + threadIdx.x;
    if (i < nwords) p[i] = 0u;
}

// ---------------------------------------------------------------------------
// Histogram of destination nodes (edges + self loops). edge_index int32.
// ---------------------------------------------------------------------------
__global__ void hist_kernel(const int* __restrict__ ei, int* __restrict__ counts,
                            int eraw, int etot, int n_nodes) {
    int e = blockIdx.x * blockDim.x + threadIdx.x;
    if (e >= etot) return;
    int dst = (e < eraw) ? ei[eraw + e] : (e - eraw);
    dst = min(max(dst, 0), n_nodes - 1);
    atomicAdd(&counts[dst], 1);
}

// ---------------------------------------------------------------------------
// Single-block scan via per-thread serial chunk + wave shuffle scan.
// ---------------------------------------------------------------------------
__global__ __launch_bounds__(1024) void scan_kernel(const int* __restrict__ counts,
                                                    int* __restrict__ indptr,
                                                    int* __restrict__ cursor, int n) {
    __shared__ int wsum[16];
    int t = threadIdx.x;
    int per = (n + 1023) >> 10;
    int base = t * per;
    int mysum = 0;
    for (int j = 0; j < per; j++) {
        int i = base + j;
        if (i < n) mysum += counts[i];
    }
    int lane = t & 63, wid = t >> 6;
    int s = mysum;
#pragma unroll
    for (int d = 1; d < 64; d <<= 1) {
        int u = __shfl_up(s, d);
        if (lane >= d) s += u;
    }
    if (lane == 63) wsum[wid] = s;
    __syncthreads();
    if (wid == 0) {
        int v = (lane < 16) ? wsum[lane] : 0;
#pragma unroll
        for (int d = 1; d < 16; d <<= 1) {
            int u = __shfl_up(v, d);
            if (lane >= d) v += u;
        }
        if (lane < 16) wsum[lane] = v;
    }
    __syncthreads();
    int waveoff = (wid == 0) ? 0 : wsum[wid - 1];
    int run = waveoff + s - mysum;   // exclusive prefix of this thread's chunk
    for (int j = 0; j < per; j++) {
        int i = base + j;
        if (i < n) {
            int c = counts[i];
            cursor[i] = run;
            run += c;
            indptr[i + 1] = run;
        }
    }
    if (t == 0) indptr[0] = 0;
}

// ---------------------------------------------------------------------------
// Fill CSR src lists
// ---------------------------------------------------------------------------
__global__ void fill_kernel(const int* __restrict__ ei, int* __restrict__ cursor,
                            int* __restrict__ csr_src, int eraw, int etot, int n_nodes) {
    int e = blockIdx.x * blockDim.x + threadIdx.x;
    if (e >= etot) return;
    int s, d;
    if (e < eraw) { s = ei[e]; d = ei[eraw + e]; }
    else          { s = d = e - eraw; }
    s = min(max(s, 0), n_nodes - 1);
    d = min(max(d, 0), n_nodes - 1);
    int pos = atomicAdd(&cursor[d], 1);
    pos = min(max(pos, 0), etot - 1);
    csr_src[pos] = s;
}

// ---------------------------------------------------------------------------
// Split-bf16 MFMA GEMM: C[M,Nc] = A[M,K] @ B[K,Nc], fp32-accurate via
// Ah*Bh + Ah*Bl + Al*Bh (3x mfma_f32_32x32x16_bf16, fp32 accumulate).
// 256 threads = 4 waves (2x2), wave tile (BM/2)x(BN/2), frags 32x32.
// OBF16: write C as RNE bf16 (ushort) instead of fp32.
// Optional fused alpha: as_out[m*AH + blockIdx.y] += dot(C_row, asrc_head).
// ---------------------------------------------------------------------------
template <int BM, int BN, int AH, bool FUSE, bool OBF16>
__global__ __launch_bounds__(256) void gemm_mfma_kernel(
    const float* __restrict__ A, const float* __restrict__ Bmat,
    void* __restrict__ Cout, int M, int K, int Nc,
    const float* __restrict__ asrc, const float* __restrict__ adst,
    float* __restrict__ as_out, float* __restrict__ ad_out)
{
    constexpr int BK = 32;
    constexpr int KS = 40;            // padded stride in shorts (80B, 16B-aligned)
    constexpr int MR = BM / 64;       // 32x32 frags per wave in M
    constexpr int NR = BN / 64;
    __shared__ short Ah[BM][KS];
    __shared__ short Al[BM][KS];
    __shared__ short Bh[BN][KS];
    __shared__ short Bl[BN][KS];

    const int tid  = threadIdx.x;
    const int lane = tid & 63;
    const int wid  = tid >> 6;
    const int wr   = wid >> 1, wc = wid & 1;
    const int bm = blockIdx.x * BM;
    const int bn = blockIdx.y * BN;

    f32x16 acc[MR][NR] = {};

    const int arow0 = tid >> 3;            // A staging: row base (32 rows/pass)
    const int acol  = (tid & 7) << 2;      // float4 col within BK
    const int bnn0  = tid & 63;            // B staging: n within 64 block
    const int bkc   = (tid >> 6) << 3;     // 8-k chunk per wave

    for (int k0 = 0; k0 < K; k0 += BK) {
        // ---- stage A (fp32 -> bf16 hi/lo) ----
#pragma unroll
        for (int i = 0; i < BM / 32; i++) {
            int r = arow0 + i * 32;
            int gr = bm + r; gr = gr < M ? gr : M - 1;
            float4 v = *(const float4*)&A[(size_t)gr * K + k0 + acol];
            float xs[4] = {v.x, v.y, v.z, v.w};
            bf4 hi, lo;
#pragma unroll
            for (int e = 0; e < 4; e++) {
                short h, l;
                split_bf(xs[e], h, l);
                hi[e] = h; lo[e] = l;
            }
            *(bf4*)&Ah[r][acol] = hi;
            *(bf4*)&Al[r][acol] = lo;
        }
        // ---- stage B transposed (fp32 row-major -> bf16 hi/lo [n][k]) ----
#pragma unroll
        for (int i = 0; i < BN / 64; i++) {
            int nn = bnn0 + i * 64;
            bf8 hi, lo;
#pragma unroll
            for (int e = 0; e < 8; e++) {
                float x = Bmat[(size_t)(k0 + bkc + e) * Nc + bn + nn];
                short h, l;
                split_bf(x, h, l);
                hi[e] = h; lo[e] = l;
            }
            *(bf8*)&Bh[nn][bkc] = hi;
            *(bf8*)&Bl[nn][bkc] = lo;
        }
        __syncthreads();
        // ---- MFMA: two K=16 chunks per BK=32 tile ----
#pragma unroll
        for (int kk = 0; kk < 2; kk++) {
            const int ki = kk * 16 + (lane >> 5) * 8;
            bf8 afh[MR], afl[MR], bfh[NR], bfl[NR];
#pragma unroll
            for (int mr = 0; mr < MR; mr++) {
                int r = wr * (BM / 2) + mr * 32 + (lane & 31);
                afh[mr] = *(const bf8*)&Ah[r][ki];
                afl[mr] = *(const bf8*)&Al[r][ki];
            }
#pragma unroll
            for (int nr = 0; nr < NR; nr++) {
                int cn = wc * (BN / 2) + nr * 32 + (lane & 31);
                bfh[nr] = *(const bf8*)&Bh[cn][ki];
                bfl[nr] = *(const bf8*)&Bl[cn][ki];
            }
#pragma unroll
            for (int mr = 0; mr < MR; mr++)
#pragma unroll
                for (int nr = 0; nr < NR; nr++) {
                    acc[mr][nr] = __builtin_amdgcn_mfma_f32_32x32x16_bf16(afh[mr], bfh[nr], acc[mr][nr], 0, 0, 0);
                    acc[mr][nr] = __builtin_amdgcn_mfma_f32_32x32x16_bf16(afh[mr], bfl[nr], acc[mr][nr], 0, 0, 0);
                    acc[mr][nr] = __builtin_amdgcn_mfma_f32_32x32x16_bf16(afl[mr], bfh[nr], acc[mr][nr], 0, 0, 0);
                }
        }
        __syncthreads();
    }

    // ---- C write: 32x32 frag C/D map: col = lane&31, row = (reg&3)+8*(reg>>2)+4*(lane>>5)
    const int hl = lane >> 5;
    const int cl = lane & 31;
#pragma unroll
    for (int mr = 0; mr < MR; mr++)
#pragma unroll
        for (int reg = 0; reg < 16; reg++) {
            int rloc = (reg & 3) + 8 * (reg >> 2) + 4 * hl;
            int m = bm + wr * (BM / 2) + mr * 32 + rloc;
            if (m < M) {
#pragma unroll
                for (int nr = 0; nr < NR; nr++) {
                    int cn = bn + wc * (BN / 2) + nr * 32 + cl;
                    if constexpr (OBF16) {
                        ((unsigned short*)Cout)[(size_t)m * Nc + cn] = f2bf_rne(acc[mr][nr][reg]);
                    } else {
                        ((float*)Cout)[(size_t)m * Nc + cn] = acc[mr][nr][reg];
                    }
                }
            }
        }

    if constexpr (FUSE) {
        // fused attention-coefficient dots over this block's BN channels (fp32 acc)
        const float* asp = asrc + (size_t)blockIdx.y * BN;
        const float* adp = adst + (size_t)blockIdx.y * BN;
#pragma unroll
        for (int mr = 0; mr < MR; mr++)
#pragma unroll
            for (int reg = 0; reg < 16; reg++) {
                float s = 0.f, d = 0.f;
#pragma unroll
                for (int nr = 0; nr < NR; nr++) {
                    int ch = wc * (BN / 2) + nr * 32 + cl;
                    float v = acc[mr][nr][reg];
                    s += v * asp[ch];
                    d += v * adp[ch];
                }
#pragma unroll
                for (int off = 16; off; off >>= 1) {
                    s += __shfl_xor(s, off);
                    d += __shfl_xor(d, off);
                }
                if (cl == 0) {
                    int rloc = (reg & 3) + 8 * (reg >> 2) + 4 * hl;
                    int m = bm + wr * (BM / 2) + mr * 32 + rloc;
                    if (m < M) {
                        atomicAdd(&as_out[(size_t)m * AH + blockIdx.y], s);
                        atomicAdd(&ad_out[(size_t)m * AH + blockIdx.y], d);
                    }
                }
            }
    }
}

// ---------------------------------------------------------------------------
// Layer-1 aggregation (+bias +ReLU): one block (256 thr) per dst node.
// h1 stored as bf16 (halves gather traffic). 4 edge parities x 64
// channel-octs; each thread loads 8 bf16 = 16 B per edge. Weights staged
// once per 64-edge tile in LDS. fp32 accumulation; parity partials via LDS.
// ---------------------------------------------------------------------------
__global__ __launch_bounds__(256) void agg1_kernel(const unsigned short* __restrict__ h1b,
                                                   const float* __restrict__ as,
                                                   const float* __restrict__ ad,
                                                   const int* __restrict__ indptr,
                                                   const int* __restrict__ csr_src,
                                                   const float* __restrict__ b1,
                                                   float* __restrict__ out1) {
    int n = blockIdx.x;
    int t = threadIdx.x;
    int q = t >> 6;                 // edge parity 0..3
    int u = t & 63;                 // channel oct: channels 8u..8u+7
    int c = u << 3;
    int hh = u >> 4;                // head = c/128
    __shared__ int   s_src[64];
    __shared__ float s_w[64][4];
    __shared__ float s_pacc[3][64][8];
    __shared__ float s_pden[3][64];
    int p0 = indptr[n], p1 = indptr[n + 1];
    float acc[8] = {};
    float den = 0.f;
    for (int base = p0; base < p1; base += 64) {
        int cnt = min(64, p1 - base);
        __syncthreads();
        if (t < cnt) {
            int s = csr_src[base + t];
            s_src[t] = s;
            float4 av = *(const float4*)&as[(size_t)s * HEADS];
            float4 dv = *(const float4*)&ad[(size_t)n * HEADS];
            float e0 = av.x + dv.x, e1 = av.y + dv.y, e2 = av.z + dv.z, e3 = av.w + dv.w;
            e0 = e0 > 0.f ? e0 : NEG_SLOPE * e0;
            e1 = e1 > 0.f ? e1 : NEG_SLOPE * e1;
            e2 = e2 > 0.f ? e2 : NEG_SLOPE * e2;
            e3 = e3 > 0.f ? e3 : NEG_SLOPE * e3;
            s_w[t][0] = __expf(e0);
            s_w[t][1] = __expf(e1);
            s_w[t][2] = __expf(e2);
            s_w[t][3] = __expf(e3);
        }
        __syncthreads();
        for (int j4 = 0; j4 < cnt; j4 += 4) {
            int j = j4 + q;
            if (j < cnt) {
                int s = s_src[j];
                float w = s_w[j][hh];
                u16x8 hv = *(const u16x8*)&h1b[(size_t)s * D1 + c];
#pragma unroll
                for (int e = 0; e < 8; e++) acc[e] += w * bf2f(hv[e]);
                den += w;
            }
        }
    }
    // combine 4 parity partials
    __syncthreads();
    if (q > 0) {
#pragma unroll
        for (int e = 0; e < 8; e++) s_pacc[q - 1][u][e] = acc[e];
        s_pden[q - 1][u] = den;
    }
    __syncthreads();
    if (q == 0) {
#pragma unroll
        for (int pp = 0; pp < 3; pp++) {
#pragma unroll
            for (int e = 0; e < 8; e++) acc[e] += s_pacc[pp][u][e];
            den += s_pden[pp][u];
        }
        float inv = 1.0f / (den + 1e-16f);
        float4 bv0 = *(const float4*)&b1[c];
        float4 bv1 = *(const float4*)&b1[c + 4];
        float4 o0, o1;
        o0.x = fmaxf(acc[0] * inv + bv0.x, 0.f);
        o0.y = fmaxf(acc[1] * inv + bv0.y, 0.f);
        o0.z = fmaxf(acc[2] * inv + bv0.z, 0.f);
        o0.w = fmaxf(acc[3] * inv + bv0.w, 0.f);
        o1.x = fmaxf(acc[4] * inv + bv1.x, 0.f);
        o1.y = fmaxf(acc[5] * inv + bv1.y, 0.f);
        o1.z = fmaxf(acc[6] * inv + bv1.z, 0.f);
        o1.w = fmaxf(acc[7] * inv + bv1.w, 0.f);
        *(float4*)&out1[(size_t)n * D1 + c]     = o0;
        *(float4*)&out1[(size_t)n * D1 + c + 4] = o1;
    }
}

// ---------------------------------------------------------------------------
// Layer-2 aggregation (+bias): one wave per dst node. Half-wave parity eq
// handles edges p2+eq; lanes 0..31 cover the 64 channels via float2 (8B).
// Partials combined with __shfl_xor(32).
// ---------------------------------------------------------------------------
__global__ __launch_bounds__(256) void agg2_kernel(const float* __restrict__ h2,
                                                   const float* __restrict__ as,
                                                   const float* __restrict__ ad,
                                                   const int* __restrict__ indptr,
                                                   const int* __restrict__ csr_src,
                                                   const float* __restrict__ b2,
                                                   float* __restrict__ out,
                                                   int n_nodes) {
    int lane = threadIdx.x & 63;
    int n = blockIdx.x * (blockDim.x >> 6) + (threadIdx.x >> 6);
    if (n >= n_nodes) return;
    int eq = lane >> 5;            // edge parity for this half-wave
    int c  = (lane & 31) * 2;      // channels c, c+1
    int p0 = indptr[n], p1 = indptr[n + 1];
    float accx = 0.f, accy = 0.f, den = 0.f;
    float adn = ad[n];
    for (int p2 = p0; p2 < p1; p2 += 2) {
        int p = p2 + eq;
        if (p < p1) {
            int s = csr_src[p];
            float e = as[s] + adn;
            e = e > 0.f ? e : NEG_SLOPE * e;
            float w = __expf(e);
            den += w;
            float2 hv = *(const float2*)&h2[(size_t)s * OUT_DIM + c];
            accx += w * hv.x;
            accy += w * hv.y;
        }
    }
    accx += __shfl_xor(accx, 32);
    accy += __shfl_xor(accy, 32);
    den  += __shfl_xor(den, 32);
    if (eq == 0) {
        float inv = 1.0f / (den + 1e-16f);
        float2 o = make_float2(accx * inv + b2[c], accy * inv + b2[c + 1]);
        *(float2*)&out[(size_t)n * OUT_DIM + c] = o;
    }
}

// ---------------------------------------------------------------------------
extern "C" void kernel_launch(void* const* d_in, const int* in_sizes, int n_in,
                              void* d_out, int out_size, void* d_ws, size_t ws_size,
                              hipStream_t stream) {
    const float* x      = (const float*)d_in[0];
    const int*   ei     = (const int*)d_in[1];
    const float* W1     = (const float*)d_in[2];
    const float* a_src1 = (const float*)d_in[3];
    const float* a_dst1 = (const float*)d_in[4];
    const float* b1     = (const float*)d_in[5];
    const float* W2     = (const float*)d_in[6];
    const float* a_src2 = (const float*)d_in[7];
    const float* a_dst2 = (const float*)d_in[8];
    const float* b2     = (const float*)d_in[9];
    float* out = (float*)d_out;

    const int n    = in_sizes[0] / IN_DIM;   // 20000
    const int eraw = in_sizes[1] / 2;        // 320000
    const int etot = eraw + n;               // 340000

    // workspace layout (~70 MB)
    char* base = (char*)d_ws;
    size_t off = 0;
    auto carve = [&](size_t bytes) { char* p = base + off; off = (off + bytes + 255) & ~(size_t)255; return p; };
    unsigned short* h1b = (unsigned short*)carve((size_t)n * D1 * 2);   // bf16, 20.5 MB
    float* out1    = (float*)carve((size_t)n * D1 * 4);
    float* h2      = (float*)carve((size_t)n * OUT_DIM * 4);
    // contiguous zero region: counts + alpha accumulators
    int*   counts  = (int*)carve((size_t)n * 4);
    float* as1     = (float*)carve((size_t)n * HEADS * 4);
    float* ad1     = (float*)carve((size_t)n * HEADS * 4);
    float* as2     = (float*)carve((size_t)n * 4);
    float* ad2     = (float*)carve((size_t)n * 4);
    char*  zend    = base + off;
    int*   cursor  = (int*)carve((size_t)n * 4);
    int*   indptr  = (int*)carve((size_t)(n + 1) * 4);
    int*   csr_src = (int*)carve((size_t)etot * 4);
    (void)ws_size;

    // ---- init + CSR build ----
    int zwords = (int)((zend - (char*)counts) / 4);
    zero_kernel<<<(zwords + 255) / 256, 256, 0, stream>>>((unsigned*)counts, zwords);
    hist_kernel<<<(etot + 255) / 256, 256, 0, stream>>>(ei, counts, eraw, etot, n);
    scan_kernel<<<1, 1024, 0, stream>>>(counts, indptr, cursor, n);
    fill_kernel<<<(etot + 255) / 256, 256, 0, stream>>>(ei, cursor, csr_src, eraw, etot, n);

    // ---- Layer 1: h1(bf16) = x @ W1  (+ fused alpha dots in fp32) ----
    {
        dim3 grid((n + 127) / 128, D1 / 128);   // blockIdx.y == head
        gemm_mfma_kernel<128, 128, HEADS, true, true><<<grid, 256, 0, stream>>>(
            x, W1, (void*)h1b, n, IN_DIM, D1, a_src1, a_dst1, as1, ad1);
    }
    agg1_kernel<<<n, 256, 0, stream>>>(h1b, as1, ad1, indptr, csr_src, b1, out1);

    // ---- Layer 2: h2 = out1 @ W2  (+ fused alpha dots) ----
    {
        dim3 grid((n + 63) / 64, 1);
        gemm_mfma_kernel<64, 64, 1, true, false><<<grid, 256, 0, stream>>>(
            out1, W2, (void*)h2, n, D1, OUT_DIM, a_src2, a_dst2, as2, ad2);
    }
    agg2_kernel<<<(n + 3) / 4, 256, 0, stream>>>(h2, as2, ad2, indptr, csr_src, b2, out, n);
}